// Round 1
// baseline (97.201 us; speedup 1.0000x reference)
//
#include <hip/hip_runtime.h>

#define TPB 256
#define RQ 4                 // query points per thread (ILP + LDS amortization)
#define QTILE (TPB * RQ)     // 1024 queries per block
#define TTILE 512            // target points staged in LDS per block

// Set output to +FLT_MAX bits before atomic-min accumulation.
__global__ void cd_init(unsigned int* out, int n) {
    int i = blockIdx.x * TPB + threadIdx.x;
    if (i < n) out[i] = 0x7F7FFFFFu;  // FLT_MAX
}

// One kernel handles both directions: blockIdx.z = b*2 + dir.
// dir==0: queries=xyz1 (dist1), targets=xyz2.  dir==1: swapped (dist2).
__global__ void __launch_bounds__(TPB, 4) cd_main(
        const float* __restrict__ xyz1, const float* __restrict__ xyz2,
        unsigned int* __restrict__ out, int B, int N, int M) {
    __shared__ float lds[TTILE * 3];

    const int zi  = blockIdx.z;
    const int b   = zi >> 1;
    const int dir = zi & 1;

    const float* q = dir ? (xyz2 + (size_t)b * M * 3) : (xyz1 + (size_t)b * N * 3);
    const float* t = dir ? (xyz1 + (size_t)b * N * 3) : (xyz2 + (size_t)b * M * 3);
    unsigned int* o = out + (dir ? ((size_t)B * N + (size_t)b * M) : ((size_t)b * N));

    // Stage this block's target tile into LDS (flat, coalesced copy).
    const float* tt = t + (size_t)blockIdx.x * (TTILE * 3);
    for (int i = threadIdx.x; i < TTILE * 3; i += TPB)
        lds[i] = tt[i];
    __syncthreads();

    // Load this thread's RQ query points into registers.
    const int q0 = blockIdx.y * QTILE + threadIdx.x;
    float qx[RQ], qy[RQ], qz[RQ], best[RQ];
    #pragma unroll
    for (int r = 0; r < RQ; ++r) {
        int qi = q0 + r * TPB;
        qx[r] = q[qi * 3 + 0];
        qy[r] = q[qi * 3 + 1];
        qz[r] = q[qi * 3 + 2];
        best[r] = 3.402823466e+38f;
    }

    // Scan the target tile. All lanes read the same LDS address -> broadcast,
    // no bank conflicts. unroll 4 -> 48B consecutive -> ds_read_b128-able.
    #pragma unroll 4
    for (int j = 0; j < TTILE; ++j) {
        float tx = lds[3 * j + 0];
        float ty = lds[3 * j + 1];
        float tz = lds[3 * j + 2];
        #pragma unroll
        for (int r = 0; r < RQ; ++r) {
            float dx = qx[r] - tx;
            float dy = qy[r] - ty;
            float dz = qz[r] - tz;
            float d  = dx * dx + dy * dy + dz * dz;
            best[r]  = fminf(best[r], d);
        }
    }

    // Nonnegative floats: IEEE order == unsigned-int order -> atomicMin on bits.
    #pragma unroll
    for (int r = 0; r < RQ; ++r)
        atomicMin(o + (q0 + r * TPB), __float_as_uint(best[r]));
}

extern "C" void kernel_launch(void* const* d_in, const int* in_sizes, int n_in,
                              void* d_out, int out_size, void* d_ws, size_t ws_size,
                              hipStream_t stream) {
    const float* xyz1 = (const float*)d_in[0];
    const float* xyz2 = (const float*)d_in[1];
    unsigned int* out = (unsigned int*)d_out;

    const int B = 4, N = 8192, M = 8192;

    cd_init<<<dim3((out_size + TPB - 1) / TPB), TPB, 0, stream>>>(out, out_size);

    // grid.x: target tiles (16), grid.y: query tiles (8), grid.z: batch*dir (8)
    dim3 grid(M / TTILE, N / QTILE, B * 2);
    cd_main<<<grid, TPB, 0, stream>>>(xyz1, xyz2, out, B, N, M);
}

// Round 2
// 47.317 us; speedup vs baseline: 2.0542x; 2.0542x over previous
//
#include <hip/hip_runtime.h>

#define TPB 256
#define RQ 8                  // query points per thread
#define QTILE (TPB * RQ)      // 2048 queries per block
#define TTILE 256             // targets staged in LDS per block
#define OFFSET 128.0f         // keeps accumulated f' = 128 + d - ||q||^2 > 0

// d_out accumulates f' = min_t (128 + ||t||^2 - 2 q.t) as uint bits.
__global__ void cd_init(unsigned int* out, int n) {
    int i = blockIdx.x * TPB + threadIdx.x;
    if (i < n) out[i] = 0x7F7FFFFFu;  // FLT_MAX
}

// blockIdx.z = b*2 + dir. dir==0: queries=xyz1, targets=xyz2 (dist1); dir==1 swapped.
__global__ void __launch_bounds__(TPB) cd_main(
        const float* __restrict__ xyz1, const float* __restrict__ xyz2,
        unsigned int* __restrict__ out, int B, int N, int M) {
    __shared__ float4 lds[TTILE];

    const int zi  = blockIdx.z;
    const int b   = zi >> 1;
    const int dir = zi & 1;

    const float* q = dir ? (xyz2 + (size_t)b * M * 3) : (xyz1 + (size_t)b * N * 3);
    const float* t = dir ? (xyz1 + (size_t)b * N * 3) : (xyz2 + (size_t)b * M * 3);
    unsigned int* o = out + (dir ? ((size_t)B * N + (size_t)b * M) : ((size_t)b * N));

    // Stage target tile: (tx,ty,tz, 128+||t||^2). TTILE == TPB: one per thread.
    {
        const int j = threadIdx.x;
        const float* tp = t + ((size_t)blockIdx.x * TTILE + j) * 3;
        float tx = tp[0], ty = tp[1], tz = tp[2];
        lds[j] = make_float4(tx, ty, tz,
                             OFFSET + __builtin_fmaf(tx, tx, __builtin_fmaf(ty, ty, tz * tz)));
    }
    __syncthreads();

    // Per-thread queries: m = -2q so the pair cost is a pure 3-FMA chain.
    const int q0 = blockIdx.y * QTILE + threadIdx.x;
    float mx[RQ], my[RQ], mz[RQ], best[RQ];
    #pragma unroll
    for (int r = 0; r < RQ; ++r) {
        const float* qp = q + (size_t)(q0 + r * TPB) * 3;
        mx[r] = -2.0f * qp[0];
        my[r] = -2.0f * qp[1];
        mz[r] = -2.0f * qp[2];
        best[r] = 3.402823466e+38f;
    }

    // 2 targets per step -> fminf(fminf(f0,f1),best) fuses to v_min3_f32.
    // All lanes read the same LDS address -> broadcast, conflict-free.
    #pragma unroll 2
    for (int j = 0; j < TTILE; j += 2) {
        float4 t0 = lds[j];
        float4 t1 = lds[j + 1];
        #pragma unroll
        for (int r = 0; r < RQ; ++r) {
            float f0 = __builtin_fmaf(t0.x, mx[r],
                       __builtin_fmaf(t0.y, my[r],
                       __builtin_fmaf(t0.z, mz[r], t0.w)));
            float f1 = __builtin_fmaf(t1.x, mx[r],
                       __builtin_fmaf(t1.y, my[r],
                       __builtin_fmaf(t1.z, mz[r], t1.w)));
            best[r] = fminf(fminf(f0, f1), best[r]);
        }
    }

    // f' > 0 guaranteed by OFFSET -> IEEE order == uint order.
    #pragma unroll
    for (int r = 0; r < RQ; ++r)
        atomicMin(o + (q0 + r * TPB), __float_as_uint(best[r]));
}

// In-place: out[i] = f' - 128 + ||q_i||^2
__global__ void cd_finalize(const float* __restrict__ xyz1, const float* __restrict__ xyz2,
                            float* __restrict__ out, int B, int N, int M) {
    int i = blockIdx.x * TPB + threadIdx.x;
    int total = B * N + B * M;
    if (i >= total) return;
    const float* qp;
    if (i < B * N) {
        qp = xyz1 + (size_t)i * 3;            // [B*N][3] flat
    } else {
        qp = xyz2 + (size_t)(i - B * N) * 3;  // [B*M][3] flat
    }
    float f  = __uint_as_float(((const unsigned int*)out)[i]);
    float sq = __builtin_fmaf(qp[0], qp[0],
               __builtin_fmaf(qp[1], qp[1], qp[2] * qp[2]));
    out[i] = f - OFFSET + sq;
}

extern "C" void kernel_launch(void* const* d_in, const int* in_sizes, int n_in,
                              void* d_out, int out_size, void* d_ws, size_t ws_size,
                              hipStream_t stream) {
    const float* xyz1 = (const float*)d_in[0];
    const float* xyz2 = (const float*)d_in[1];

    const int B = 4, N = 8192, M = 8192;

    cd_init<<<dim3((out_size + TPB - 1) / TPB), TPB, 0, stream>>>((unsigned int*)d_out, out_size);

    // grid.x: target tiles (32), grid.y: query tiles (4), grid.z: batch*dir (8)
    dim3 grid(M / TTILE, N / QTILE, B * 2);
    cd_main<<<grid, TPB, 0, stream>>>(xyz1, xyz2, (unsigned int*)d_out, B, N, M);

    cd_finalize<<<dim3((out_size + TPB - 1) / TPB), TPB, 0, stream>>>(
        xyz1, xyz2, (float*)d_out, B, N, M);
}